// Round 1
// baseline (397.487 us; speedup 1.0000x reference)
//
#include <hip/hip_runtime.h>
#include <math.h>

#define DIMC 1024
#define BB   8
#define LL   2048
#define ACTC 256
#define HIDC 256
#define EPSV 1e-6f
#define MROWS (BB * LL)   // 16384
#define NCHUNK 32
#define LC     64         // LL / NCHUNK

typedef __bf16 bf16x8 __attribute__((ext_vector_type(8)));
typedef float  f32x4  __attribute__((ext_vector_type(4)));

__device__ __forceinline__ unsigned short f2bf(float f) {
    union { float f; unsigned int u; } v; v.f = f;
    unsigned int u = v.u + 0x7fffu + ((v.u >> 16) & 1u);
    return (unsigned short)(u >> 16);
}
__device__ __forceinline__ float bf2f(unsigned short s) {
    union { float f; unsigned int u; } v; v.u = ((unsigned int)s) << 16;
    return v.f;
}
// inf-safe fast sigmoid/tanh on native v_exp_f32
__device__ __forceinline__ float fast_sigmoid(float x) {
    return 1.0f / (1.0f + __expf(-x));
}
__device__ __forceinline__ float fast_tanh(float x) {
    float ax = fabsf(x);
    float t = 1.0f - 2.0f / (__expf(2.0f * ax) + 1.0f);  // exp(inf)->inf -> t=1
    return copysignf(t, x);
}

// ---------------- weight convert: all 5 weights in one launch ----------------
__global__ void k_convert5(const float* __restrict__ s0, const float* __restrict__ s1,
                           const float* __restrict__ s2, const float* __restrict__ s3,
                           const float* __restrict__ s4,
                           unsigned short* __restrict__ d0, unsigned short* __restrict__ d1,
                           unsigned short* __restrict__ d2, unsigned short* __restrict__ d3,
                           unsigned short* __restrict__ d4) {
    int i = blockIdx.x * blockDim.x + threadIdx.x;  // total 3670016
    if (i < 1048576)            d0[i]           = f2bf(s0[i]);
    else if (i < 2097152)       d1[i - 1048576] = f2bf(s1[i - 1048576]);
    else if (i < 3145728)       d2[i - 2097152] = f2bf(s2[i - 2097152]);
    else if (i < 3407872)       d3[i - 3145728] = f2bf(s3[i - 3145728]);
    else if (i < 3670016)       d4[i - 3407872] = f2bf(s4[i - 3407872]);
}

// ---------------- RMSNorm: one block per row, bf16 out ----------------
__global__ __launch_bounds__(256) void k_rmsnorm(const float* __restrict__ x,
                                                 const float* __restrict__ w,
                                                 unsigned short* __restrict__ xnb) {
    int m = blockIdx.x;
    int t = threadIdx.x;
    float4 v = ((const float4*)(x + (size_t)m * DIMC))[t];
    float ss = v.x*v.x + v.y*v.y + v.z*v.z + v.w*v.w;
#pragma unroll
    for (int off = 32; off > 0; off >>= 1) ss += __shfl_down(ss, off, 64);
    __shared__ float sred[4];
    if ((t & 63) == 0) sred[t >> 6] = ss;
    __syncthreads();
    float tot = sred[0] + sred[1] + sred[2] + sred[3];
    float rinv = 1.0f / sqrtf(tot * (1.0f / DIMC) + EPSV);
    float4 wv = ((const float4*)w)[t];
    uint2 o;
    o.x = (unsigned)f2bf(wv.x * v.x * rinv) | ((unsigned)f2bf(wv.y * v.y * rinv) << 16);
    o.y = (unsigned)f2bf(wv.z * v.z * rinv) | ((unsigned)f2bf(wv.w * v.w * rinv) << 16);
    ((uint2*)(xnb + (size_t)m * DIMC))[t] = o;
}

// ---------------- depthwise conv K=5, zero-pad, bf16 in/out ----------------
__global__ __launch_bounds__(256) void k_dwconv(const unsigned short* __restrict__ xnb,
                                                const float* __restrict__ dww,
                                                const float* __restrict__ dwb,
                                                unsigned short* __restrict__ xc) {
    int m = blockIdx.x;          // b*LL + l
    int l = m & (LL - 1);
    int t = threadIdx.x;         // channel group of 4
    int c0 = t * 4;
    float wgt[4][5];
#pragma unroll
    for (int j = 0; j < 4; ++j)
#pragma unroll
        for (int k = 0; k < 5; ++k) wgt[j][k] = dww[(c0 + j) * 5 + k];
    float4 bv = ((const float4*)dwb)[t];
    float acc[4] = {bv.x, bv.y, bv.z, bv.w};
#pragma unroll
    for (int k = 0; k < 5; ++k) {
        int ll = l + k - 2;
        if (ll < 0 || ll >= LL) continue;
        uint2 rv = ((const uint2*)(xnb + (size_t)(m + k - 2) * DIMC))[t];
        acc[0] += bf2f((unsigned short)(rv.x & 0xffff)) * wgt[0][k];
        acc[1] += bf2f((unsigned short)(rv.x >> 16))    * wgt[1][k];
        acc[2] += bf2f((unsigned short)(rv.y & 0xffff)) * wgt[2][k];
        acc[3] += bf2f((unsigned short)(rv.y >> 16))    * wgt[3][k];
    }
    uint2 o;
    o.x = (unsigned)f2bf(acc[0]) | ((unsigned)f2bf(acc[1]) << 16);
    o.y = (unsigned)f2bf(acc[2]) | ((unsigned)f2bf(acc[3]) << 16);
    ((uint2*)(xc + (size_t)m * DIMC))[t] = o;
}

// ---------------- chunked parallel scan ----------------
__global__ __launch_bounds__(256) void k_scan_a(const unsigned short* __restrict__ xnb,
                                                const float* __restrict__ alpha,
                                                const float* __restrict__ beta,
                                                float* __restrict__ F) {
    int blk = blockIdx.x;        // b*NCHUNK + k
    int b = blk >> 5, k = blk & (NCHUNK - 1);
    int c = threadIdx.x;
    float a = alpha[c], bt = beta[c];
    const unsigned short* p = xnb + ((size_t)(b * LL + k * LC)) * DIMC + c;
    float h = 0.0f;
    for (int l = 0; l < LC; ++l) h = a * h + bt * bf2f(p[(size_t)l * DIMC]);
    F[(size_t)blk * ACTC + c] = h;
}
__global__ __launch_bounds__(256) void k_scan_b(const float* __restrict__ alpha,
                                                const float* __restrict__ F,
                                                float* __restrict__ Cv) {
    int b = blockIdx.x;
    int c = threadIdx.x;
    float a = alpha[c];
    float aL = a;
#pragma unroll
    for (int i = 0; i < 6; ++i) aL *= aL;   // a^64
    float T = 0.0f;
    for (int k = 0; k < NCHUNK; ++k) {
        size_t idx = ((size_t)b * NCHUNK + k) * ACTC + c;
        Cv[idx] = T;
        T = F[idx] + aL * T;
    }
}
__global__ __launch_bounds__(256) void k_scan_c(const unsigned short* __restrict__ xnb,
                                                const float* __restrict__ alpha,
                                                const float* __restrict__ beta,
                                                const float* __restrict__ Cv,
                                                unsigned short* __restrict__ hs) {
    int blk = blockIdx.x;
    int b = blk >> 5, k = blk & (NCHUNK - 1);
    int c = threadIdx.x;
    float a = alpha[c], bt = beta[c];
    const unsigned short* p = xnb + ((size_t)(b * LL + k * LC)) * DIMC + c;
    unsigned short*       q = hs  + ((size_t)(b * LL + k * LC)) * ACTC + c;
    float h = Cv[(size_t)blk * ACTC + c];
    for (int l = 0; l < LC; ++l) {
        h = a * h + bt * bf2f(p[(size_t)l * DIMC]);
        q[(size_t)l * ACTC] = f2bf(h);
    }
}

// ---------------- legacy 128x128 MFMA GEMM (kept for MODE 2 and 3) ----------------
// NOTE: MODE1 must stay at launch_bounds(256,2) — (256,3) caps VGPRs at ~85 and
// spills the 2x 4x4 f32x4 accumulators to scratch (R5: WRITE_SIZE 32->121MB, 2.2x slower).
#define TM 128
#define TN 128
#define BK 64

#define GLOAD_LDS(gp, lp) \
    __builtin_amdgcn_global_load_lds((const __attribute__((address_space(1))) unsigned int*)(gp), \
                                     (__attribute__((address_space(3))) unsigned int*)(lp), 16, 0, 0)

template<int MODE>
__global__ __launch_bounds__(256, (MODE == 1) ? 2 : 4) void k_gemm(
        const unsigned short* __restrict__ A,
        const unsigned short* __restrict__ B0,
        const unsigned short* __restrict__ B1,
        const float* __restrict__ bias0,
        const float* __restrict__ bias1,
        const unsigned short* __restrict__ add0,
        const unsigned short* __restrict__ add1,
        const float* __restrict__ addf,
        float* __restrict__ outf,
        unsigned short* __restrict__ outb,
        int M, int N, int K)
{
    constexpr int LDSB = (MODE == 1) ? 49152 : 32768;
    __shared__ __align__(16) char lds[LDSB];
    unsigned short* sA  = (unsigned short*)lds;
    unsigned short* sB0 = (unsigned short*)(lds + 16384);
    unsigned short* sB1 = (unsigned short*)(lds + 32768);

    int nx = gridDim.x;
    int bid = blockIdx.y * nx + blockIdx.x;
    int xcd = bid & 7, s = bid >> 3;
    int colt = s % nx, rowgrp = s / nx;
    int m0 = (rowgrp * 8 + xcd) * TM;
    int n0 = colt * TN;

    int t = threadIdx.x;
    int w = t >> 6, lane = t & 63;
    int wm = (w >> 1) * 64, wn = (w & 1) * 64;
    int quad = lane >> 4, lm = lane & 15;
    int lm7 = lm & 7;

    f32x4 zero = {0.f, 0.f, 0.f, 0.f};
    f32x4 acc0[4][4];
    f32x4 acc1[(MODE == 1) ? 4 : 1][(MODE == 1) ? 4 : 1];
#pragma unroll
    for (int i = 0; i < 4; ++i)
#pragma unroll
        for (int j = 0; j < 4; ++j) acc0[i][j] = zero;
    if constexpr (MODE == 1) {
#pragma unroll
        for (int i = 0; i < 4; ++i)
#pragma unroll
            for (int j = 0; j < 4; ++j) acc1[i][j] = zero;
    }

    for (int k0 = 0; k0 < K; k0 += BK) {
        __syncthreads();
#pragma unroll
        for (int c = 0; c < 4; ++c) {
            int i = t + c * 256;
            int r = i >> 3;
            int sc = ((i & 7) ^ (r & 7)) << 3;   // swizzled source k-group
            GLOAD_LDS(A  + (size_t)(m0 + r) * K + k0 + sc, sA  + i * 8);
            GLOAD_LDS(B0 + (size_t)(n0 + r) * K + k0 + sc, sB0 + i * 8);
            if constexpr (MODE == 1)
                GLOAD_LDS(B1 + (size_t)(n0 + r) * K + k0 + sc, sB1 + i * 8);
        }
        __syncthreads();

#pragma unroll
        for (int ks = 0; ks < BK; ks += 32) {
            int cgb = ks >> 3;   // 0 or 4
            bf16x8 af[4], b0f[4];
#pragma unroll
            for (int i = 0; i < 4; ++i) {
                int sg = ((cgb + quad) ^ lm7) << 3;
                af[i]  = *(const bf16x8*)(sA  + (wm + i * 16 + lm) * BK + sg);
                b0f[i] = *(const bf16x8*)(sB0 + (wn + i * 16 + lm) * BK + sg);
            }
            if constexpr (MODE == 1) {
                bf16x8 b1f[4];
#pragma unroll
                for (int i = 0; i < 4; ++i)
                    b1f[i] = *(const bf16x8*)(sB1 + (wn + i * 16 + lm) * BK + (((cgb + quad) ^ lm7) << 3));
#pragma unroll
                for (int mi = 0; mi < 4; ++mi)
#pragma unroll
                    for (int ni = 0; ni < 4; ++ni) {
                        acc0[mi][ni] = __builtin_amdgcn_mfma_f32_16x16x32_bf16(af[mi], b0f[ni], acc0[mi][ni], 0, 0, 0);
                        acc1[mi][ni] = __builtin_amdgcn_mfma_f32_16x16x32_bf16(af[mi], b1f[ni], acc1[mi][ni], 0, 0, 0);
                    }
            } else {
#pragma unroll
                for (int mi = 0; mi < 4; ++mi)
#pragma unroll
                    for (int ni = 0; ni < 4; ++ni)
                        acc0[mi][ni] = __builtin_amdgcn_mfma_f32_16x16x32_bf16(af[mi], b0f[ni], acc0[mi][ni], 0, 0, 0);
            }
        }
    }

    __syncthreads();
    if constexpr (MODE == 3) {
        float* sO = (float*)lds;
#pragma unroll
        for (int half = 0; half < 2; ++half) {
            if (wm == half * 64) {
#pragma unroll
                for (int mi = 0; mi < 4; ++mi) {
#pragma unroll
                    for (int ni = 0; ni < 4; ++ni) {
                        int nl = wn + ni * 16 + lm;
                        float bn = bias0[n0 + nl];
#pragma unroll
                        for (int j = 0; j < 4; ++j) {
                            int mloc = mi * 16 + quad * 4 + j;   // 0..63
                            sO[mloc * TN + nl] = acc0[mi][ni][j] + bn;
                        }
                    }
                }
            }
            __syncthreads();
#pragma unroll
            for (int c = 0; c < 8; ++c) {
                int i = t + c * 256;
                int r = i >> 5, c4 = (i & 31) << 2;
                int m = m0 + half * 64 + r, n = n0 + c4;
                float4 v  = *(float4*)(sO + r * TN + c4);
                uint2  ab = *(const uint2*)(add0 + (size_t)m * N + n);
                float4 xf = *(const float4*)(addf + (size_t)m * N + n);
                float4 o;
                o.x = v.x + bf2f((unsigned short)(ab.x & 0xffff)) + xf.x;
                o.y = v.y + bf2f((unsigned short)(ab.x >> 16))    + xf.y;
                o.z = v.z + bf2f((unsigned short)(ab.y & 0xffff)) + xf.z;
                o.w = v.w + bf2f((unsigned short)(ab.y >> 16))    + xf.w;
                *(float4*)(outf + (size_t)m * N + n) = o;
            }
            __syncthreads();
        }
    } else {
        unsigned short* sO = (unsigned short*)lds;
#pragma unroll
        for (int mi = 0; mi < 4; ++mi) {
#pragma unroll
            for (int ni = 0; ni < 4; ++ni) {
                int nl = wn + ni * 16 + lm;
                int n  = n0 + nl;
                float bn = bias0[n];
                float bn1 = (MODE == 1) ? bias1[n] : 0.0f;
#pragma unroll
                for (int j = 0; j < 4; ++j) {
                    int ml = wm + mi * 16 + quad * 4 + j;
                    float v = acc0[mi][ni][j];
                    float r;
                    if constexpr (MODE == 0) {
                        r = v + bn;
                    } else if constexpr (MODE == 1) {
                        float u1 = v + bn;
                        float u2 = acc1[mi][ni][j] + bn1;
                        r = fast_sigmoid(u1) * fast_tanh(u2);
                    } else { // MODE 2
                        float u = v + bn;
                        r = 0.5f * u * (1.0f + erff(u * 0.70710678118654752f));
                    }
                    sO[ml * TN + nl] = f2bf(r);
                }
            }
        }
        __syncthreads();
#pragma unroll
        for (int c = 0; c < 8; ++c) {
            int i = t + c * 256;
            int r = i >> 4, c8 = (i & 15) << 3;
            int m = m0 + r, n = n0 + c8;
            uint4 g = *(uint4*)(sO + r * TN + c8);
            if constexpr (MODE == 2) {
                *(uint4*)(outb + (size_t)m * N + n) = g;
            } else {
                uint4 av;
                if constexpr (MODE == 0) {
                    av = (n0 < ACTC) ? *(const uint4*)(add0 + (size_t)m * ACTC + n)
                                     : *(const uint4*)(add1 + (size_t)m * DIMC + n);
                } else {
                    av = *(const uint4*)(add0 + (size_t)m * N + n);
                }
                unsigned* gp = (unsigned*)&g;
                unsigned* ap = (unsigned*)&av;
                uint4 o;
                unsigned* op = (unsigned*)&o;
#pragma unroll
                for (int q = 0; q < 4; ++q) {
                    float lo = bf2f((unsigned short)(gp[q] & 0xffff)) + bf2f((unsigned short)(ap[q] & 0xffff));
                    float hi = bf2f((unsigned short)(gp[q] >> 16))    + bf2f((unsigned short)(ap[q] >> 16));
                    op[q] = (unsigned)f2bf(lo) | ((unsigned)f2bf(hi) << 16);
                }
                *(uint4*)(outb + (size_t)m * N + n) = o;
            }
        }
    }
}

// ================== 256-row-tile 8-phase GEMM (MODE 0 and 1) ==================
// T3+T4+T2+T5 port of the verified 256^2 8-phase template (learn_hip m194-m201):
//   512 thr / 8 waves (2M x 4N), BM=256, BK=64, 128 KiB double-buffered dynamic LDS.
//   Per K-tile, 4 phases x {ds_read subtile; 2x global_load_lds; s_barrier;
//   setprio(1); 16 MFMA; setprio(0); s_barrier}. Raw s_barrier (no waitcnt drain);
//   ONE counted s_waitcnt vmcnt(6) per K-tile -- loads stay in flight across barriers.
// Schedule invariants (write-after-read safety, all verified region-by-region):
//   P1 reads ALL B-frags (both k-steps) + A(h0,s0)   -> B region free from P2
//   P2 reads A(h0,s1)                                -> A rows {0-63,128-191} free from P3
//   P3 reads A(h1,s0), P4 reads A(h1,s1)             -> A rows {64-127,192-255} free after P4
//   stages: P1 -> A-odd-quarters(tau+1) [other buf]; P2 -> B-lo(tau+2);
//           P3 -> A-even-quarters(tau+2); P4 -> B-hi(tau+2) [current buf, freed regions]
//   => at end-P4 exactly 6 loads newer than everything tile tau+1 needs: vmcnt(6).
// XOR k-group swizzle + fragment indexing copied from the verified 128^2 kernel
// (linear gload_lds dest + pre-swizzled global source + swizzled ds_read).

#define STG8(gb, rb, kq, dsto) \
    __builtin_amdgcn_global_load_lds( \
        (const __attribute__((address_space(1))) unsigned int*)((gb) + (size_t)(rb) * DIMC + (kq)), \
        (__attribute__((address_space(3))) unsigned int*)(sb + (dsto) + (rb) * 64 + t * 8), 16, 0, 0)

#define FENCE asm volatile("" ::: "memory")
#define BAR   do { FENCE; __builtin_amdgcn_s_barrier(); FENCE; } while (0)

#define READ_A(h, s) \
    do { \
        _Pragma("unroll") \
        for (int i = 0; i < 4; ++i) { \
            int ar = wm * 128 + (h) * 64 + i * 16 + lm; \
            af[i] = *(const bf16x8*)(sb + bO + ar * 64 + ((((s) * 4 + quad) ^ lm7) << 3)); \
        } \
    } while (0)

#define PHASE_MFMA(h, s) \
    do { \
        __builtin_amdgcn_s_setprio(1); \
        _Pragma("unroll") \
        for (int i = 0; i < 4; ++i) { \
            _Pragma("unroll") \
            for (int j = 0; j < NBF; ++j) { \
                acc0[(h) * 4 + i][j] = __builtin_amdgcn_mfma_f32_16x16x32_bf16(af[i], bf0[s][j], acc0[(h) * 4 + i][j], 0, 0, 0); \
                if constexpr (MODE == 1) \
                    acc1[(h) * 4 + i][j] = __builtin_amdgcn_mfma_f32_16x16x32_bf16(af[i], bf1[s][j], acc1[(h) * 4 + i][j], 0, 0, 0); \
            } \
        } \
        __builtin_amdgcn_s_setprio(0); \
    } while (0)

template<int MODE>   // 0: +bias +concat-residual(hs|xnb); 1: dual-B GLU +residual
__global__ __launch_bounds__(512, 1) void k_gemm8(
        const unsigned short* __restrict__ A,
        const unsigned short* __restrict__ B0,
        const unsigned short* __restrict__ B1,
        const float* __restrict__ bias0,
        const float* __restrict__ bias1,
        const unsigned short* __restrict__ add0,
        const unsigned short* __restrict__ add1,
        unsigned short* __restrict__ outb)
{
    constexpr int BN  = (MODE == 1) ? 128 : 256;   // per-B output cols per block
    constexpr int WBN = BN / 4;                    // per-wave cols (32 or 64)
    constexpr int NBF = WBN / 16;                  // B frags per k-step (2 or 4)
    constexpr int NTN = DIMC / BN;                 // col tiles (8 or 4)
    constexpr int NT  = DIMC / 64;                 // 16 K-tiles

    extern __shared__ __align__(16) char lds[];
    unsigned short* sb = (unsigned short*)lds;
    // per-buffer layout (shorts): A[256][64] @ +0 ; B0 @ +16384 ; (MODE1) B1 @ +24576
    // buffer stride 32768 shorts (64 KiB); total 128 KiB.

    int bid = blockIdx.x;
    int xcd = bid & 7, sgrp = bid >> 3;
    int colt = sgrp % NTN, rowgrp = sgrp / NTN;    // col fastest within XCD chunk
    int m0 = (rowgrp * 8 + xcd) * 256;
    int n0 = colt * BN;

    int t = threadIdx.x;
    int w = t >> 6, lane = t & 63;
    int wm = w >> 2, wn = w & 3;                   // 2 x 4 wave grid
    int quad = lane >> 4, lm = lane & 15, lm7 = lm & 7;
    int rl = t >> 3;                               // stage row-in-round 0..63
    int scv = ((t & 7) ^ (rl & 7)) << 3;           // pre-swizzled source k-offset

    const unsigned short* Ab  = A  + (size_t)(m0 + rl) * DIMC + scv;
    const unsigned short* B0b = B0 + (size_t)(n0 + rl) * DIMC + scv;
    const unsigned short* B1b = (MODE == 1) ? (B1 + (size_t)(n0 + rl) * DIMC + scv) : (const unsigned short*)0;

    f32x4 zero = {0.f, 0.f, 0.f, 0.f};
    f32x4 acc0[8][NBF];
    f32x4 acc1[8][NBF];
#pragma unroll
    for (int i = 0; i < 8; ++i)
#pragma unroll
        for (int j = 0; j < NBF; ++j) acc0[i][j] = zero;
    if constexpr (MODE == 1) {
#pragma unroll
        for (int i = 0; i < 8; ++i)
#pragma unroll
            for (int j = 0; j < NBF; ++j) acc1[i][j] = zero;
    }

    // ---------------- prologue: tile0 (8 rounds, oldest) + tile1 (6 rounds) ----------------
    STG8(Ab, 0, 0, 0); STG8(Ab, 128, 0, 0);
    STG8(B0b, 0, 0, 16384); STG8(B0b, 64, 0, 16384);
    if constexpr (MODE == 0) { STG8(B0b, 128, 0, 16384); STG8(B0b, 192, 0, 16384); }
    else                     { STG8(B1b, 0, 0, 24576);   STG8(B1b, 64, 0, 24576); }
    STG8(Ab, 64, 0, 0); STG8(Ab, 192, 0, 0);
    // tile1 -> buf1, issue order mirrors steady-state P2/P3/P4
    STG8(B0b, 0, 64, 32768 + 16384); STG8(B0b, 64, 64, 32768 + 16384);
    STG8(Ab, 0, 64, 32768); STG8(Ab, 128, 64, 32768);
    if constexpr (MODE == 0) { STG8(B0b, 128, 64, 32768 + 16384); STG8(B0b, 192, 64, 32768 + 16384); }
    else                     { STG8(B1b, 0, 64, 32768 + 24576);   STG8(B1b, 64, 64, 32768 + 24576); }
    asm volatile("s_waitcnt vmcnt(6)" ::: "memory");   // tile0's 8 rounds landed
    BAR;

    bf16x8 bf0[2][NBF];
    bf16x8 bf1[2][NBF];

#pragma unroll 2
    for (int tau = 0; tau < NT; ++tau) {
        const int bO  = (tau & 1) << 15;           // current buffer (shorts)
        const int bN  = ((tau & 1) ^ 1) << 15;     // other buffer
        const int kq1 = (tau + 1) << 6;
        const int kq2 = (tau + 2) << 6;
        const bool g1v = (tau + 1 < NT), g2v = (tau + 2 < NT);
        bf16x8 af[4];

        // ---------- P1: read ALL B-frags + A(h0,s0); stage A-odd(tau+1) ----------
#pragma unroll
        for (int ss = 0; ss < 2; ++ss)
#pragma unroll
            for (int j = 0; j < NBF; ++j) {
                int br = wn * WBN + j * 16 + lm;
                int sl = ((ss * 4 + quad) ^ lm7) << 3;
                bf0[ss][j] = *(const bf16x8*)(sb + bO + 16384 + br * 64 + sl);
                if constexpr (MODE == 1)
                    bf1[ss][j] = *(const bf16x8*)(sb + bO + 24576 + br * 64 + sl);
            }
        READ_A(0, 0);
        if (g1v) { STG8(Ab, 64, kq1, bN); STG8(Ab, 192, kq1, bN); }
        BAR;
        PHASE_MFMA(0, 0);
        BAR;

        // ---------- P2: read A(h0,s1); stage B-lo(tau+2) ----------
        READ_A(0, 1);
        if (g2v) { STG8(B0b, 0, kq2, bO + 16384); STG8(B0b, 64, kq2, bO + 16384); }
        BAR;
        PHASE_MFMA(0, 1);
        BAR;

        // ---------- P3: read A(h1,s0); stage A-even(tau+2) ----------
        READ_A(1, 0);
        if (g2v) { STG8(Ab, 0, kq2, bO); STG8(Ab, 128, kq2, bO); }
        BAR;
        PHASE_MFMA(1, 0);
        BAR;

        // ---------- P4: read A(h1,s1); stage B-hi(tau+2); counted vmcnt ----------
        READ_A(1, 1);
        if (g2v) {
            if constexpr (MODE == 0) { STG8(B0b, 128, kq2, bO + 16384); STG8(B0b, 192, kq2, bO + 16384); }
            else                     { STG8(B1b, 0, kq2, bO + 24576);   STG8(B1b, 64, kq2, bO + 24576); }
        }
        BAR;
        PHASE_MFMA(1, 1);
        if (tau < NT - 2)        asm volatile("s_waitcnt vmcnt(6)" ::: "memory");
        else if (tau == NT - 2)  asm volatile("s_waitcnt vmcnt(0)" ::: "memory");
        BAR;
    }

    // ---------------- epilogue: acc -> bf16 LDS pack -> coalesced store + adds ----------------
    unsigned short* sO = sb;   // reuse: [256][BN] bf16 (128 KiB / 64 KiB)
    __syncthreads();
#pragma unroll
    for (int mi = 0; mi < 8; ++mi) {
#pragma unroll
        for (int ni = 0; ni < NBF; ++ni) {
            int nl = wn * WBN + ni * 16 + lm;
            float bn = bias0[n0 + nl];
            float bn1 = 0.f;
            if constexpr (MODE == 1) bn1 = bias1[n0 + nl];
#pragma unroll
            for (int j = 0; j < 4; ++j) {
                int ml = wm * 128 + mi * 16 + quad * 4 + j;
                float r;
                if constexpr (MODE == 0) {
                    r = acc0[mi][ni][j] + bn;
                } else {
                    float u1 = acc0[mi][ni][j] + bn;
                    float u2 = acc1[mi][ni][j] + bn1;
                    r = fast_sigmoid(u1) * fast_tanh(u2);
                }
                sO[ml * BN + nl] = f2bf(r);
            }
        }
    }
    __syncthreads();
#pragma unroll
    for (int c = 0; c < ((MODE == 0) ? 16 : 8); ++c) {
        int i = t + c * 512;
        int r = i / (BN / 8);
        int g = i % (BN / 8);
        int m = m0 + r, n = n0 + g * 8;
        uint4 gv = *(uint4*)(sO + r * BN + g * 8);
        const unsigned short* ap;
        if constexpr (MODE == 0)
            ap = (colt == 0) ? (add0 + (size_t)m * ACTC + n) : (add1 + (size_t)m * DIMC + n);
        else
            ap = add0 + (size_t)m * DIMC + n;
        uint4 av = *(const uint4*)ap;
        unsigned* gp  = (unsigned*)&gv;
        unsigned* app = (unsigned*)&av;
        uint4 o; unsigned* op = (unsigned*)&o;
#pragma unroll
        for (int q = 0; q < 4; ++q) {
            float lo = bf2f((unsigned short)(gp[q] & 0xffff)) + bf2f((unsigned short)(app[q] & 0xffff));
            float hi = bf2f((unsigned short)(gp[q] >> 16))    + bf2f((unsigned short)(app[q] >> 16));
            op[q] = (unsigned)f2bf(lo) | ((unsigned)f2bf(hi) << 16);
        }
        *(uint4*)(outb + (size_t)m * DIMC + n) = o;
    }
}

extern "C" void kernel_launch(void* const* d_in, const int* in_sizes, int n_in,
                              void* d_out, int out_size, void* d_ws, size_t ws_size,
                              hipStream_t stream) {
    (void)in_sizes; (void)n_in; (void)out_size; (void)ws_size;
    const float* x      = (const float*)d_in[0];
    const float* norm_w = (const float*)d_in[1];
    const float* dw_w   = (const float*)d_in[2];
    const float* dw_b   = (const float*)d_in[3];
    const float* pw_w   = (const float*)d_in[4];
    const float* pw_b   = (const float*)d_in[5];
    const float* alpha  = (const float*)d_in[6];
    const float* beta   = (const float*)d_in[7];
    const float* W1_w   = (const float*)d_in[8];
    const float* W1_b   = (const float*)d_in[9];
    const float* W2_w   = (const float*)d_in[10];
    const float* W2_b   = (const float*)d_in[11];
    const float* down_w = (const float*)d_in[12];
    const float* down_b = (const float*)d_in[13];
    const float* up_w   = (const float*)d_in[14];
    const float* up_b   = (const float*)d_in[15];

    char* ws = (char*)d_ws;
    unsigned short* xnb  = (unsigned short*)(ws);
    unsigned short* xc   = (unsigned short*)(ws + 33554432ull);
    unsigned short* hs   = (unsigned short*)(ws + 67108864ull);
    unsigned short* y1b  = (unsigned short*)(ws + 75497472ull);
    unsigned short* y2b  = (unsigned short*)(ws + 109051904ull);
    unsigned short* gact = (unsigned short*)(ws + 142606336ull);
    unsigned short* wpw  = (unsigned short*)(ws + 150994944ull);
    unsigned short* w1b  = wpw + 1048576;
    unsigned short* w2b  = w1b + 1048576;
    unsigned short* wdn  = w2b + 1048576;
    unsigned short* wup  = wdn + 262144;
    float*          Fb   = (float*)(ws + 159383552ull);
    float*          Cb   = (float*)(ws + 159383552ull + 262144ull);

    // allow 128 KiB dynamic LDS for the 8-phase GEMMs (persistent; capture-safe)
    static int attr_done = 0;
    if (!attr_done) {
        (void)hipFuncSetAttribute((const void*)&k_gemm8<0>, hipFuncAttributeMaxDynamicSharedMemorySize, 131072);
        (void)hipFuncSetAttribute((const void*)&k_gemm8<1>, hipFuncAttributeMaxDynamicSharedMemorySize, 131072);
        attr_done = 1;
    }

    k_convert5<<<14336, 256, 0, stream>>>(pw_w, W1_w, W2_w, down_w, up_w,
                                          wpw, w1b, w2b, wdn, wup);

    k_rmsnorm<<<MROWS, 256, 0, stream>>>(x, norm_w, xnb);
    k_dwconv <<<MROWS, 256, 0, stream>>>(xnb, dw_w, dw_b, xc);

    k_scan_a<<<BB * NCHUNK, ACTC, 0, stream>>>(xnb, alpha, beta, Fb);
    k_scan_b<<<BB, ACTC, 0, stream>>>(alpha, Fb, Cb);
    k_scan_c<<<BB * NCHUNK, ACTC, 0, stream>>>(xnb, alpha, beta, Cb, hs);

    // 8-phase 256-row-tile GEMMs (MODE0: pw, MODE1: GLU dual-B)
    k_gemm8<0><<<dim3((MROWS / 256) * (DIMC / 256)), dim3(512), 131072, stream>>>(
        xc, wpw, nullptr, pw_b, nullptr, hs, xnb, y1b);
    k_gemm8<1><<<dim3((MROWS / 256) * (DIMC / 128)), dim3(512), 131072, stream>>>(
        y1b, w1b, w2b, W1_b, W2_b, y1b, nullptr, y2b);

    // legacy 128^2 kernel for the small-N / small-K tail GEMMs
    dim3 g1(DIMC / TN, MROWS / TM);
    dim3 g2(HIDC / TN, MROWS / TM);
    k_gemm<2><<<g2, 256, 0, stream>>>(y2b, wdn, nullptr, down_b, nullptr, nullptr, nullptr, nullptr, nullptr, gact, MROWS, HIDC, DIMC);
    k_gemm<3><<<g1, 256, 0, stream>>>(gact, wup, nullptr, up_b, nullptr, y2b, nullptr, x, (float*)d_out, nullptr, MROWS, DIMC, HIDC);
}

// Round 2
// 378.021 us; speedup vs baseline: 1.0515x; 1.0515x over previous
//
#include <hip/hip_runtime.h>
#include <math.h>

#define DIMC 1024
#define BB   8
#define LL   2048
#define ACTC 256
#define HIDC 256
#define EPSV 1e-6f
#define MROWS (BB * LL)   // 16384
#define NCHUNK 32
#define LC     64         // LL / NCHUNK

typedef __bf16 bf16x8 __attribute__((ext_vector_type(8)));
typedef float  f32x4  __attribute__((ext_vector_type(4)));

__device__ __forceinline__ unsigned short f2bf(float f) {
    union { float f; unsigned int u; } v; v.f = f;
    unsigned int u = v.u + 0x7fffu + ((v.u >> 16) & 1u);
    return (unsigned short)(u >> 16);
}
__device__ __forceinline__ float bf2f(unsigned short s) {
    union { float f; unsigned int u; } v; v.u = ((unsigned int)s) << 16;
    return v.f;
}
// inf-safe fast sigmoid/tanh on native v_exp_f32
__device__ __forceinline__ float fast_sigmoid(float x) {
    return 1.0f / (1.0f + __expf(-x));
}
__device__ __forceinline__ float fast_tanh(float x) {
    float ax = fabsf(x);
    float t = 1.0f - 2.0f / (__expf(2.0f * ax) + 1.0f);  // exp(inf)->inf -> t=1
    return copysignf(t, x);
}

// ---------------- weight convert: all 5 weights in one launch ----------------
__global__ void k_convert5(const float* __restrict__ s0, const float* __restrict__ s1,
                           const float* __restrict__ s2, const float* __restrict__ s3,
                           const float* __restrict__ s4,
                           unsigned short* __restrict__ d0, unsigned short* __restrict__ d1,
                           unsigned short* __restrict__ d2, unsigned short* __restrict__ d3,
                           unsigned short* __restrict__ d4) {
    int i = blockIdx.x * blockDim.x + threadIdx.x;  // total 3670016
    if (i < 1048576)            d0[i]           = f2bf(s0[i]);
    else if (i < 2097152)       d1[i - 1048576] = f2bf(s1[i - 1048576]);
    else if (i < 3145728)       d2[i - 2097152] = f2bf(s2[i - 2097152]);
    else if (i < 3407872)       d3[i - 3145728] = f2bf(s3[i - 3145728]);
    else if (i < 3670016)       d4[i - 3407872] = f2bf(s4[i - 3407872]);
}

// ---------------- RMSNorm: one block per row, bf16 out ----------------
__global__ __launch_bounds__(256) void k_rmsnorm(const float* __restrict__ x,
                                                 const float* __restrict__ w,
                                                 unsigned short* __restrict__ xnb) {
    int m = blockIdx.x;
    int t = threadIdx.x;
    float4 v = ((const float4*)(x + (size_t)m * DIMC))[t];
    float ss = v.x*v.x + v.y*v.y + v.z*v.z + v.w*v.w;
#pragma unroll
    for (int off = 32; off > 0; off >>= 1) ss += __shfl_down(ss, off, 64);
    __shared__ float sred[4];
    if ((t & 63) == 0) sred[t >> 6] = ss;
    __syncthreads();
    float tot = sred[0] + sred[1] + sred[2] + sred[3];
    float rinv = 1.0f / sqrtf(tot * (1.0f / DIMC) + EPSV);
    float4 wv = ((const float4*)w)[t];
    uint2 o;
    o.x = (unsigned)f2bf(wv.x * v.x * rinv) | ((unsigned)f2bf(wv.y * v.y * rinv) << 16);
    o.y = (unsigned)f2bf(wv.z * v.z * rinv) | ((unsigned)f2bf(wv.w * v.w * rinv) << 16);
    ((uint2*)(xnb + (size_t)m * DIMC))[t] = o;
}

// ---------------- depthwise conv K=5, zero-pad, bf16 in/out ----------------
__global__ __launch_bounds__(256) void k_dwconv(const unsigned short* __restrict__ xnb,
                                                const float* __restrict__ dww,
                                                const float* __restrict__ dwb,
                                                unsigned short* __restrict__ xc) {
    int m = blockIdx.x;          // b*LL + l
    int l = m & (LL - 1);
    int t = threadIdx.x;         // channel group of 4
    int c0 = t * 4;
    float wgt[4][5];
#pragma unroll
    for (int j = 0; j < 4; ++j)
#pragma unroll
        for (int k = 0; k < 5; ++k) wgt[j][k] = dww[(c0 + j) * 5 + k];
    float4 bv = ((const float4*)dwb)[t];
    float acc[4] = {bv.x, bv.y, bv.z, bv.w};
#pragma unroll
    for (int k = 0; k < 5; ++k) {
        int ll = l + k - 2;
        if (ll < 0 || ll >= LL) continue;
        uint2 rv = ((const uint2*)(xnb + (size_t)(m + k - 2) * DIMC))[t];
        acc[0] += bf2f((unsigned short)(rv.x & 0xffff)) * wgt[0][k];
        acc[1] += bf2f((unsigned short)(rv.x >> 16))    * wgt[1][k];
        acc[2] += bf2f((unsigned short)(rv.y & 0xffff)) * wgt[2][k];
        acc[3] += bf2f((unsigned short)(rv.y >> 16))    * wgt[3][k];
    }
    uint2 o;
    o.x = (unsigned)f2bf(acc[0]) | ((unsigned)f2bf(acc[1]) << 16);
    o.y = (unsigned)f2bf(acc[2]) | ((unsigned)f2bf(acc[3]) << 16);
    ((uint2*)(xc + (size_t)m * DIMC))[t] = o;
}

// ---------------- chunked parallel scan ----------------
__global__ __launch_bounds__(256) void k_scan_a(const unsigned short* __restrict__ xnb,
                                                const float* __restrict__ alpha,
                                                const float* __restrict__ beta,
                                                float* __restrict__ F) {
    int blk = blockIdx.x;        // b*NCHUNK + k
    int b = blk >> 5, k = blk & (NCHUNK - 1);
    int c = threadIdx.x;
    float a = alpha[c], bt = beta[c];
    const unsigned short* p = xnb + ((size_t)(b * LL + k * LC)) * DIMC + c;
    float h = 0.0f;
    for (int l = 0; l < LC; ++l) h = a * h + bt * bf2f(p[(size_t)l * DIMC]);
    F[(size_t)blk * ACTC + c] = h;
}
__global__ __launch_bounds__(256) void k_scan_b(const float* __restrict__ alpha,
                                                const float* __restrict__ F,
                                                float* __restrict__ Cv) {
    int b = blockIdx.x;
    int c = threadIdx.x;
    float a = alpha[c];
    float aL = a;
#pragma unroll
    for (int i = 0; i < 6; ++i) aL *= aL;   // a^64
    float T = 0.0f;
    for (int k = 0; k < NCHUNK; ++k) {
        size_t idx = ((size_t)b * NCHUNK + k) * ACTC + c;
        Cv[idx] = T;
        T = F[idx] + aL * T;
    }
}
__global__ __launch_bounds__(256) void k_scan_c(const unsigned short* __restrict__ xnb,
                                                const float* __restrict__ alpha,
                                                const float* __restrict__ beta,
                                                const float* __restrict__ Cv,
                                                unsigned short* __restrict__ hs) {
    int blk = blockIdx.x;
    int b = blk >> 5, k = blk & (NCHUNK - 1);
    int c = threadIdx.x;
    float a = alpha[c], bt = beta[c];
    const unsigned short* p = xnb + ((size_t)(b * LL + k * LC)) * DIMC + c;
    unsigned short*       q = hs  + ((size_t)(b * LL + k * LC)) * ACTC + c;
    float h = Cv[(size_t)blk * ACTC + c];
    for (int l = 0; l < LC; ++l) {
        h = a * h + bt * bf2f(p[(size_t)l * DIMC]);
        q[(size_t)l * ACTC] = f2bf(h);
    }
}

// ---------------- legacy 128x128 MFMA GEMM (MODE 0, 2, 3) ----------------
// NOTE: MODE1 legacy variant kept compiling but unused.
#define TM 128
#define TN 128
#define BK 64

#define GLOAD_LDS(gp, lp) \
    __builtin_amdgcn_global_load_lds((const __attribute__((address_space(1))) unsigned int*)(gp), \
                                     (__attribute__((address_space(3))) unsigned int*)(lp), 16, 0, 0)

template<int MODE>
__global__ __launch_bounds__(256, (MODE == 1) ? 2 : 4) void k_gemm(
        const unsigned short* __restrict__ A,
        const unsigned short* __restrict__ B0,
        const unsigned short* __restrict__ B1,
        const float* __restrict__ bias0,
        const float* __restrict__ bias1,
        const unsigned short* __restrict__ add0,
        const unsigned short* __restrict__ add1,
        const float* __restrict__ addf,
        float* __restrict__ outf,
        unsigned short* __restrict__ outb,
        int M, int N, int K)
{
    constexpr int LDSB = (MODE == 1) ? 49152 : 32768;
    __shared__ __align__(16) char lds[LDSB];
    unsigned short* sA  = (unsigned short*)lds;
    unsigned short* sB0 = (unsigned short*)(lds + 16384);
    unsigned short* sB1 = (unsigned short*)(lds + 32768);

    int nx = gridDim.x;
    int bid = blockIdx.y * nx + blockIdx.x;
    int xcd = bid & 7, s = bid >> 3;
    int colt = s % nx, rowgrp = s / nx;
    int m0 = (rowgrp * 8 + xcd) * TM;
    int n0 = colt * TN;

    int t = threadIdx.x;
    int w = t >> 6, lane = t & 63;
    int wm = (w >> 1) * 64, wn = (w & 1) * 64;
    int quad = lane >> 4, lm = lane & 15;
    int lm7 = lm & 7;

    f32x4 zero = {0.f, 0.f, 0.f, 0.f};
    f32x4 acc0[4][4];
    f32x4 acc1[(MODE == 1) ? 4 : 1][(MODE == 1) ? 4 : 1];
#pragma unroll
    for (int i = 0; i < 4; ++i)
#pragma unroll
        for (int j = 0; j < 4; ++j) acc0[i][j] = zero;
    if constexpr (MODE == 1) {
#pragma unroll
        for (int i = 0; i < 4; ++i)
#pragma unroll
            for (int j = 0; j < 4; ++j) acc1[i][j] = zero;
    }

    for (int k0 = 0; k0 < K; k0 += BK) {
        __syncthreads();
#pragma unroll
        for (int c = 0; c < 4; ++c) {
            int i = t + c * 256;
            int r = i >> 3;
            int sc = ((i & 7) ^ (r & 7)) << 3;   // swizzled source k-group
            GLOAD_LDS(A  + (size_t)(m0 + r) * K + k0 + sc, sA  + i * 8);
            GLOAD_LDS(B0 + (size_t)(n0 + r) * K + k0 + sc, sB0 + i * 8);
            if constexpr (MODE == 1)
                GLOAD_LDS(B1 + (size_t)(n0 + r) * K + k0 + sc, sB1 + i * 8);
        }
        __syncthreads();

#pragma unroll
        for (int ks = 0; ks < BK; ks += 32) {
            int cgb = ks >> 3;   // 0 or 4
            bf16x8 af[4], b0f[4];
#pragma unroll
            for (int i = 0; i < 4; ++i) {
                int sg = ((cgb + quad) ^ lm7) << 3;
                af[i]  = *(const bf16x8*)(sA  + (wm + i * 16 + lm) * BK + sg);
                b0f[i] = *(const bf16x8*)(sB0 + (wn + i * 16 + lm) * BK + sg);
            }
            if constexpr (MODE == 1) {
                bf16x8 b1f[4];
#pragma unroll
                for (int i = 0; i < 4; ++i)
                    b1f[i] = *(const bf16x8*)(sB1 + (wn + i * 16 + lm) * BK + (((cgb + quad) ^ lm7) << 3));
#pragma unroll
                for (int mi = 0; mi < 4; ++mi)
#pragma unroll
                    for (int ni = 0; ni < 4; ++ni) {
                        acc0[mi][ni] = __builtin_amdgcn_mfma_f32_16x16x32_bf16(af[mi], b0f[ni], acc0[mi][ni], 0, 0, 0);
                        acc1[mi][ni] = __builtin_amdgcn_mfma_f32_16x16x32_bf16(af[mi], b1f[ni], acc1[mi][ni], 0, 0, 0);
                    }
            } else {
#pragma unroll
                for (int mi = 0; mi < 4; ++mi)
#pragma unroll
                    for (int ni = 0; ni < 4; ++ni)
                        acc0[mi][ni] = __builtin_amdgcn_mfma_f32_16x16x32_bf16(af[mi], b0f[ni], acc0[mi][ni], 0, 0, 0);
            }
        }
    }

    __syncthreads();
    if constexpr (MODE == 3) {
        float* sO = (float*)lds;
#pragma unroll
        for (int half = 0; half < 2; ++half) {
            if (wm == half * 64) {
#pragma unroll
                for (int mi = 0; mi < 4; ++mi) {
#pragma unroll
                    for (int ni = 0; ni < 4; ++ni) {
                        int nl = wn + ni * 16 + lm;
                        float bn = bias0[n0 + nl];
#pragma unroll
                        for (int j = 0; j < 4; ++j) {
                            int mloc = mi * 16 + quad * 4 + j;   // 0..63
                            sO[mloc * TN + nl] = acc0[mi][ni][j] + bn;
                        }
                    }
                }
            }
            __syncthreads();
#pragma unroll
            for (int c = 0; c < 8; ++c) {
                int i = t + c * 256;
                int r = i >> 5, c4 = (i & 31) << 2;
                int m = m0 + half * 64 + r, n = n0 + c4;
                float4 v  = *(float4*)(sO + r * TN + c4);
                uint2  ab = *(const uint2*)(add0 + (size_t)m * N + n);
                float4 xf = *(const float4*)(addf + (size_t)m * N + n);
                float4 o;
                o.x = v.x + bf2f((unsigned short)(ab.x & 0xffff)) + xf.x;
                o.y = v.y + bf2f((unsigned short)(ab.x >> 16))    + xf.y;
                o.z = v.z + bf2f((unsigned short)(ab.y & 0xffff)) + xf.z;
                o.w = v.w + bf2f((unsigned short)(ab.y >> 16))    + xf.w;
                *(float4*)(outf + (size_t)m * N + n) = o;
            }
            __syncthreads();
        }
    } else {
        unsigned short* sO = (unsigned short*)lds;
#pragma unroll
        for (int mi = 0; mi < 4; ++mi) {
#pragma unroll
            for (int ni = 0; ni < 4; ++ni) {
                int nl = wn + ni * 16 + lm;
                int n  = n0 + nl;
                float bn = bias0[n];
                float bn1 = (MODE == 1) ? bias1[n] : 0.0f;
#pragma unroll
                for (int j = 0; j < 4; ++j) {
                    int ml = wm + mi * 16 + quad * 4 + j;
                    float v = acc0[mi][ni][j];
                    float r;
                    if constexpr (MODE == 0) {
                        r = v + bn;
                    } else if constexpr (MODE == 1) {
                        float u1 = v + bn;
                        float u2 = acc1[mi][ni][j] + bn1;
                        r = fast_sigmoid(u1) * fast_tanh(u2);
                    } else { // MODE 2
                        float u = v + bn;
                        r = 0.5f * u * (1.0f + erff(u * 0.70710678118654752f));
                    }
                    sO[ml * TN + nl] = f2bf(r);
                }
            }
        }
        __syncthreads();
#pragma unroll
        for (int c = 0; c < 8; ++c) {
            int i = t + c * 256;
            int r = i >> 4, c8 = (i & 15) << 3;
            int m = m0 + r, n = n0 + c8;
            uint4 g = *(uint4*)(sO + r * TN + c8);
            if constexpr (MODE == 2) {
                *(uint4*)(outb + (size_t)m * N + n) = g;
            } else {
                uint4 av;
                if constexpr (MODE == 0) {
                    av = (n0 < ACTC) ? *(const uint4*)(add0 + (size_t)m * ACTC + n)
                                     : *(const uint4*)(add1 + (size_t)m * DIMC + n);
                } else {
                    av = *(const uint4*)(add0 + (size_t)m * N + n);
                }
                unsigned* gp = (unsigned*)&g;
                unsigned* ap = (unsigned*)&av;
                uint4 o;
                unsigned* op = (unsigned*)&o;
#pragma unroll
                for (int q = 0; q < 4; ++q) {
                    float lo = bf2f((unsigned short)(gp[q] & 0xffff)) + bf2f((unsigned short)(ap[q] & 0xffff));
                    float hi = bf2f((unsigned short)(gp[q] >> 16))    + bf2f((unsigned short)(ap[q] >> 16));
                    op[q] = (unsigned)f2bf(lo) | ((unsigned)f2bf(hi) << 16);
                }
                *(uint4*)(outb + (size_t)m * N + n) = o;
            }
        }
    }
}

// ================== 256-row-tile 8-phase GEMM (MODE 1 this round) ==================
// Round-2 delta vs round-1 (A/B isolated): NO memory-clobber fences around the raw
// s_barrier (the template has none; 8 clobbers/K-tile walled off all cross-phase
// scheduling overlap), and the template's explicit `s_waitcnt lgkmcnt(0)` after the
// pre-MFMA barrier. Ordering safety without fences:
//   - ds_read vs global_load_lds may-alias in LDS -> compiler preserves program order
//   - ds_reads cannot hoist above the vmcnt asm (it keeps its "memory" clobber),
//     which is the only point where LDS-DMA completion matters
//   - STG8 issue-order at the vmcnt count points is likewise pinned by that clobber
// Schedule (unchanged, verified round-1 via pass + count audit):
//   P1 reads ALL B-frags + A(h0,s0) -> B region free from P2
//   P2 reads A(h0,s1) -> A rows {0-63,128-191} free from P3
//   P3 reads A(h1,s0), P4 reads A(h1,s1)
//   stages: P1 -> A-odd(tau+1)[other buf]; P2 -> B-lo(tau+2); P3 -> A-even(tau+2);
//           P4 -> B-hi(tau+2) [current buf, freed regions]; vmcnt(6) once per K-tile.

#define STG8(gb, rb, kq, dsto) \
    __builtin_amdgcn_global_load_lds( \
        (const __attribute__((address_space(1))) unsigned int*)((gb) + (size_t)(rb) * DIMC + (kq)), \
        (__attribute__((address_space(3))) unsigned int*)(sb + (dsto) + (rb) * 64 + t * 8), 16, 0, 0)

#define BAR __builtin_amdgcn_s_barrier()

#define READ_A(h, s) \
    do { \
        _Pragma("unroll") \
        for (int i = 0; i < 4; ++i) { \
            int ar = wm * 128 + (h) * 64 + i * 16 + lm; \
            af[i] = *(const bf16x8*)(sb + bO + ar * 64 + ((((s) * 4 + quad) ^ lm7) << 3)); \
        } \
    } while (0)

#define PHASE_MFMA(h, s) \
    do { \
        asm volatile("s_waitcnt lgkmcnt(0)"); \
        __builtin_amdgcn_s_setprio(1); \
        _Pragma("unroll") \
        for (int i = 0; i < 4; ++i) { \
            _Pragma("unroll") \
            for (int j = 0; j < NBF; ++j) { \
                acc0[(h) * 4 + i][j] = __builtin_amdgcn_mfma_f32_16x16x32_bf16(af[i], bf0[s][j], acc0[(h) * 4 + i][j], 0, 0, 0); \
                if constexpr (MODE == 1) \
                    acc1[(h) * 4 + i][j] = __builtin_amdgcn_mfma_f32_16x16x32_bf16(af[i], bf1[s][j], acc1[(h) * 4 + i][j], 0, 0, 0); \
            } \
        } \
        __builtin_amdgcn_s_setprio(0); \
    } while (0)

template<int MODE>   // 0: +bias +concat-residual(hs|xnb); 1: dual-B GLU +residual
__global__ __launch_bounds__(512, 1) void k_gemm8(
        const unsigned short* __restrict__ A,
        const unsigned short* __restrict__ B0,
        const unsigned short* __restrict__ B1,
        const float* __restrict__ bias0,
        const float* __restrict__ bias1,
        const unsigned short* __restrict__ add0,
        const unsigned short* __restrict__ add1,
        unsigned short* __restrict__ outb)
{
    constexpr int BN  = (MODE == 1) ? 128 : 256;   // per-B output cols per block
    constexpr int WBN = BN / 4;                    // per-wave cols (32 or 64)
    constexpr int NBF = WBN / 16;                  // B frags per k-step (2 or 4)
    constexpr int NTN = DIMC / BN;                 // col tiles (8 or 4)
    constexpr int NT  = DIMC / 64;                 // 16 K-tiles

    extern __shared__ __align__(16) char lds[];
    unsigned short* sb = (unsigned short*)lds;
    // per-buffer layout (shorts): A[256][64] @ +0 ; B0 @ +16384 ; (MODE1) B1 @ +24576
    // buffer stride 32768 shorts (64 KiB); total 128 KiB.

    int bid = blockIdx.x;
    int xcd = bid & 7, sgrp = bid >> 3;
    int colt = sgrp % NTN, rowgrp = sgrp / NTN;    // col fastest within XCD chunk
    int m0 = (rowgrp * 8 + xcd) * 256;
    int n0 = colt * BN;

    int t = threadIdx.x;
    int w = t >> 6, lane = t & 63;
    int wm = w >> 2, wn = w & 3;                   // 2 x 4 wave grid
    int quad = lane >> 4, lm = lane & 15, lm7 = lm & 7;
    int rl = t >> 3;                               // stage row-in-round 0..63
    int scv = ((t & 7) ^ (rl & 7)) << 3;           // pre-swizzled source k-offset

    const unsigned short* Ab  = A  + (size_t)(m0 + rl) * DIMC + scv;
    const unsigned short* B0b = B0 + (size_t)(n0 + rl) * DIMC + scv;
    const unsigned short* B1b = (MODE == 1) ? (B1 + (size_t)(n0 + rl) * DIMC + scv) : (const unsigned short*)0;

    f32x4 zero = {0.f, 0.f, 0.f, 0.f};
    f32x4 acc0[8][NBF];
    f32x4 acc1[8][NBF];
#pragma unroll
    for (int i = 0; i < 8; ++i)
#pragma unroll
        for (int j = 0; j < NBF; ++j) acc0[i][j] = zero;
    if constexpr (MODE == 1) {
#pragma unroll
        for (int i = 0; i < 8; ++i)
#pragma unroll
            for (int j = 0; j < NBF; ++j) acc1[i][j] = zero;
    }

    // ---------------- prologue: tile0 (8 rounds, oldest) + tile1 (6 rounds) ----------------
    STG8(Ab, 0, 0, 0); STG8(Ab, 128, 0, 0);
    STG8(B0b, 0, 0, 16384); STG8(B0b, 64, 0, 16384);
    if constexpr (MODE == 0) { STG8(B0b, 128, 0, 16384); STG8(B0b, 192, 0, 16384); }
    else                     { STG8(B1b, 0, 0, 24576);   STG8(B1b, 64, 0, 24576); }
    STG8(Ab, 64, 0, 0); STG8(Ab, 192, 0, 0);
    // tile1 -> buf1, issue order mirrors steady-state P2/P3/P4
    STG8(B0b, 0, 64, 32768 + 16384); STG8(B0b, 64, 64, 32768 + 16384);
    STG8(Ab, 0, 64, 32768); STG8(Ab, 128, 64, 32768);
    if constexpr (MODE == 0) { STG8(B0b, 128, 64, 32768 + 16384); STG8(B0b, 192, 64, 32768 + 16384); }
    else                     { STG8(B1b, 0, 64, 32768 + 24576);   STG8(B1b, 64, 64, 32768 + 24576); }
    asm volatile("s_waitcnt vmcnt(6)" ::: "memory");   // tile0's 8 rounds landed
    BAR;

    bf16x8 bf0[2][NBF];
    bf16x8 bf1[2][NBF];

#pragma unroll 2
    for (int tau = 0; tau < NT; ++tau) {
        const int bO  = (tau & 1) << 15;           // current buffer (shorts)
        const int bN  = ((tau & 1) ^ 1) << 15;     // other buffer
        const int kq1 = (tau + 1) << 6;
        const int kq2 = (tau + 2) << 6;
        const bool g1v = (tau + 1 < NT), g2v = (tau + 2 < NT);
        bf16x8 af[4];

        // ---------- P1: read ALL B-frags + A(h0,s0); stage A-odd(tau+1) ----------
#pragma unroll
        for (int ss = 0; ss < 2; ++ss)
#pragma unroll
            for (int j = 0; j < NBF; ++j) {
                int br = wn * WBN + j * 16 + lm;
                int sl = ((ss * 4 + quad) ^ lm7) << 3;
                bf0[ss][j] = *(const bf16x8*)(sb + bO + 16384 + br * 64 + sl);
                if constexpr (MODE == 1)
                    bf1[ss][j] = *(const bf16x8*)(sb + bO + 24576 + br * 64 + sl);
            }
        READ_A(0, 0);
        if (g1v) { STG8(Ab, 64, kq1, bN); STG8(Ab, 192, kq1, bN); }
        BAR;
        PHASE_MFMA(0, 0);
        BAR;

        // ---------- P2: read A(h0,s1); stage B-lo(tau+2) ----------
        READ_A(0, 1);
        if (g2v) { STG8(B0b, 0, kq2, bO + 16384); STG8(B0b, 64, kq2, bO + 16384); }
        BAR;
        PHASE_MFMA(0, 1);
        BAR;

        // ---------- P3: read A(h1,s0); stage A-even(tau+2) ----------
        READ_A(1, 0);
        if (g2v) { STG8(Ab, 0, kq2, bO); STG8(Ab, 128, kq2, bO); }
        BAR;
        PHASE_MFMA(1, 0);
        BAR;

        // ---------- P4: read A(h1,s1); stage B-hi(tau+2); counted vmcnt ----------
        READ_A(1, 1);
        if (g2v) {
            if constexpr (MODE == 0) { STG8(B0b, 128, kq2, bO + 16384); STG8(B0b, 192, kq2, bO + 16384); }
            else                     { STG8(B1b, 0, kq2, bO + 24576);   STG8(B1b, 64, kq2, bO + 24576); }
        }
        BAR;
        PHASE_MFMA(1, 1);
        if (tau < NT - 2)        asm volatile("s_waitcnt vmcnt(6)" ::: "memory");
        else if (tau == NT - 2)  asm volatile("s_waitcnt vmcnt(0)" ::: "memory");
        BAR;
    }

    // ---------------- epilogue: acc -> bf16 LDS pack -> coalesced store + adds ----------------
    unsigned short* sO = sb;   // reuse: [256][BN] bf16
    __syncthreads();
#pragma unroll
    for (int mi = 0; mi < 8; ++mi) {
#pragma unroll
        for (int ni = 0; ni < NBF; ++ni) {
            int nl = wn * WBN + ni * 16 + lm;
            float bn = bias0[n0 + nl];
            float bn1 = 0.f;
            if constexpr (MODE == 1) bn1 = bias1[n0 + nl];
#pragma unroll
            for (int j = 0; j < 4; ++j) {
                int ml = wm * 128 + mi * 16 + quad * 4 + j;
                float r;
                if constexpr (MODE == 0) {
                    r = acc0[mi][ni][j] + bn;
                } else {
                    float u1 = acc0[mi][ni][j] + bn;
                    float u2 = acc1[mi][ni][j] + bn1;
                    r = fast_sigmoid(u1) * fast_tanh(u2);
                }
                sO[ml * BN + nl] = f2bf(r);
            }
        }
    }
    __syncthreads();
#pragma unroll
    for (int c = 0; c < ((MODE == 0) ? 16 : 8); ++c) {
        int i = t + c * 512;
        int r = i / (BN / 8);
        int g = i % (BN / 8);
        int m = m0 + r, n = n0 + g * 8;
        uint4 gv = *(uint4*)(sO + r * BN + g * 8);
        const unsigned short* ap;
        if constexpr (MODE == 0)
            ap = (colt == 0) ? (add0 + (size_t)m * ACTC + n) : (add1 + (size_t)m * DIMC + n);
        else
            ap = add0 + (size_t)m * DIMC + n;
        uint4 av = *(const uint4*)ap;
        unsigned* gp  = (unsigned*)&gv;
        unsigned* app = (unsigned*)&av;
        uint4 o; unsigned* op = (unsigned*)&o;
#pragma unroll
        for (int q = 0; q < 4; ++q) {
            float lo = bf2f((unsigned short)(gp[q] & 0xffff)) + bf2f((unsigned short)(app[q] & 0xffff));
            float hi = bf2f((unsigned short)(gp[q] >> 16))    + bf2f((unsigned short)(app[q] >> 16));
            op[q] = (unsigned)f2bf(lo) | ((unsigned)f2bf(hi) << 16);
        }
        *(uint4*)(outb + (size_t)m * DIMC + n) = o;
    }
}

extern "C" void kernel_launch(void* const* d_in, const int* in_sizes, int n_in,
                              void* d_out, int out_size, void* d_ws, size_t ws_size,
                              hipStream_t stream) {
    (void)in_sizes; (void)n_in; (void)out_size; (void)ws_size;
    const float* x      = (const float*)d_in[0];
    const float* norm_w = (const float*)d_in[1];
    const float* dw_w   = (const float*)d_in[2];
    const float* dw_b   = (const float*)d_in[3];
    const float* pw_w   = (const float*)d_in[4];
    const float* pw_b   = (const float*)d_in[5];
    const float* alpha  = (const float*)d_in[6];
    const float* beta   = (const float*)d_in[7];
    const float* W1_w   = (const float*)d_in[8];
    const float* W1_b   = (const float*)d_in[9];
    const float* W2_w   = (const float*)d_in[10];
    const float* W2_b   = (const float*)d_in[11];
    const float* down_w = (const float*)d_in[12];
    const float* down_b = (const float*)d_in[13];
    const float* up_w   = (const float*)d_in[14];
    const float* up_b   = (const float*)d_in[15];

    char* ws = (char*)d_ws;
    unsigned short* xnb  = (unsigned short*)(ws);
    unsigned short* xc   = (unsigned short*)(ws + 33554432ull);
    unsigned short* hs   = (unsigned short*)(ws + 67108864ull);
    unsigned short* y1b  = (unsigned short*)(ws + 75497472ull);
    unsigned short* y2b  = (unsigned short*)(ws + 109051904ull);
    unsigned short* gact = (unsigned short*)(ws + 142606336ull);
    unsigned short* wpw  = (unsigned short*)(ws + 150994944ull);
    unsigned short* w1b  = wpw + 1048576;
    unsigned short* w2b  = w1b + 1048576;
    unsigned short* wdn  = w2b + 1048576;
    unsigned short* wup  = wdn + 262144;
    float*          Fb   = (float*)(ws + 159383552ull);
    float*          Cb   = (float*)(ws + 159383552ull + 262144ull);

    // allow 128 KiB dynamic LDS for the 8-phase GEMM (persistent; capture-safe)
    static int attr_done = 0;
    if (!attr_done) {
        (void)hipFuncSetAttribute((const void*)&k_gemm8<0>, hipFuncAttributeMaxDynamicSharedMemorySize, 131072);
        (void)hipFuncSetAttribute((const void*)&k_gemm8<1>, hipFuncAttributeMaxDynamicSharedMemorySize, 131072);
        attr_done = 1;
    }

    k_convert5<<<14336, 256, 0, stream>>>(pw_w, W1_w, W2_w, down_w, up_w,
                                          wpw, w1b, w2b, wdn, wup);

    k_rmsnorm<<<MROWS, 256, 0, stream>>>(x, norm_w, xnb);
    k_dwconv <<<MROWS, 256, 0, stream>>>(xnb, dw_w, dw_b, xc);

    k_scan_a<<<BB * NCHUNK, ACTC, 0, stream>>>(xnb, alpha, beta, Fb);
    k_scan_b<<<BB, ACTC, 0, stream>>>(alpha, Fb, Cb);
    k_scan_c<<<BB * NCHUNK, ACTC, 0, stream>>>(xnb, alpha, beta, Cb, hs);

    // MODE0: legacy 128^2 (known-good round-0 config). MODE1: fence-free 8-phase A/B.
    dim3 g1(DIMC / TN, MROWS / TM);
    dim3 g2(HIDC / TN, MROWS / TM);
    k_gemm<0><<<g1, 256, 0, stream>>>(xc, wpw, nullptr, pw_b, nullptr, hs, xnb, nullptr, nullptr, y1b, MROWS, DIMC, DIMC);
    k_gemm8<1><<<dim3((MROWS / 256) * (DIMC / 128)), dim3(512), 131072, stream>>>(
        y1b, w1b, w2b, W1_b, W2_b, y1b, nullptr, y2b);

    k_gemm<2><<<g2, 256, 0, stream>>>(y2b, wdn, nullptr, down_b, nullptr, nullptr, nullptr, nullptr, nullptr, gact, MROWS, HIDC, DIMC);
    k_gemm<3><<<g1, 256, 0, stream>>>(gact, wup, nullptr, up_b, nullptr, y2b, nullptr, x, (float*)d_out, nullptr, MROWS, DIMC, HIDC);
}